// Round 2
// baseline (3210.209 us; speedup 1.0000x reference)
//
#include <hip/hip_runtime.h>
#include <hip/hip_bf16.h>
#include <math.h>

#define NB 8
#define NT 2048
#define NC 768
#define NWD 512
#define NTD 384
#define NCD 3072
#define ROWS (NB*NT)   // 16384

// ---------------- LayerNorm: one block (256 thr) per row of 768 ----------------
__global__ __launch_bounds__(256) void ln_kernel(const float* __restrict__ x,
                                                 const float* __restrict__ g,
                                                 const float* __restrict__ b,
                                                 float* __restrict__ out) {
    int row = blockIdx.x;
    const float* xr = x + (long)row * NC;
    int t = threadIdx.x;
    float v0 = xr[t], v1 = xr[t + 256], v2 = xr[t + 512];
    float s = v0 + v1 + v2;
    float s2 = v0 * v0 + v1 * v1 + v2 * v2;
    for (int off = 32; off > 0; off >>= 1) {
        s  += __shfl_down(s, off, 64);
        s2 += __shfl_down(s2, off, 64);
    }
    __shared__ float ls[4], ls2[4];
    int wid = t >> 6, lane = t & 63;
    if (lane == 0) { ls[wid] = s; ls2[wid] = s2; }
    __syncthreads();
    if (t == 0) {
        float ts  = ls[0] + ls[1] + ls[2] + ls[3];
        float ts2 = ls2[0] + ls2[1] + ls2[2] + ls2[3];
        float mu = ts * (1.0f / NC);
        float var = ts2 * (1.0f / NC) - mu * mu;
        ls[0]  = mu;
        ls2[0] = 1.0f / sqrtf(var + 1e-6f);
    }
    __syncthreads();
    float mu = ls[0], r = ls2[0];
    float* orow = out + (long)row * NC;
    orow[t]       = (v0 - mu) * r * g[t]       + b[t];
    orow[t + 256] = (v1 - mu) * r * g[t + 256] + b[t + 256];
    orow[t + 512] = (v2 - mu) * r * g[t + 512] + b[t + 512];
}

// ---------------- style vectors: s1[8,384], s2[8,384], ss[8,1536] ----------------
// sout layout: [0,3072) s1 | [3072,6144) s2 | [6144,18432) ss
__global__ __launch_bounds__(256) void svec_kernel(const float* __restrict__ w,
                                                   const float* __restrict__ s1W, const float* __restrict__ s1b,
                                                   const float* __restrict__ s2W, const float* __restrict__ s2b,
                                                   const float* __restrict__ ssW, const float* __restrict__ ssb,
                                                   float* __restrict__ sout) {
    int gid = blockIdx.x * 256 + threadIdx.x;   // 0..18431
    int bb = gid / 2304;
    int r  = gid % 2304;
    const float* w0 = w + (long)bb * 1024;
    const float* w1 = w0 + 512;
    float acc = 0.f;
    if (r < 384) {
        for (int k = 0; k < 512; k++) acc += w0[k] * s1W[k * 384 + r];
        sout[bb * 384 + r] = acc + s1b[r];
    } else if (r < 768) {
        int c = r - 384;
        for (int k = 0; k < 512; k++) acc += w0[k] * s2W[k * 384 + c];
        sout[3072 + bb * 384 + c] = acc + s2b[c];
    } else {
        int c = r - 768;
        for (int k = 0; k < 512; k++) acc += w1[k] * ssW[k * 1536 + c];
        sout[6144 + bb * 1536 + c] = acc + ssb[c];
    }
}

// ---------------- tiled fp32 GEMM, 64x64x16, 4x4 per thread ----------------
// TRANS_A: A is [K,M]. Else A is [M,K]. B is [K,N]. C is [M,N].
// RESID: C += A@B (+bias). GELU: exact gelu. Batch via grid.z strides.
template<bool TRANS_A, bool RESID, bool GELU, bool BIAS>
__global__ __launch_bounds__(256) void gemm_f32(const float* __restrict__ A,
                                                const float* __restrict__ Bm,
                                                float* __restrict__ Cm,
                                                int M, int N, int K,
                                                long sA, long sB, long sC,
                                                const float* __restrict__ bias) {
    int z = blockIdx.z;
    A  += (long)z * sA;
    Bm += (long)z * sB;
    Cm += (long)z * sC;
    int n0 = blockIdx.x * 64;
    int m0 = blockIdx.y * 64;
    __shared__ float As[16][68];
    __shared__ float Bs[16][68];
    int t = threadIdx.x;
    int tx = t & 15, ty = t >> 4;
    float acc[4][4] = {};
    for (int k0 = 0; k0 < K; k0 += 16) {
        if (TRANS_A) {
#pragma unroll
            for (int i = 0; i < 4; i++) {
                int e = t + i * 256;
                int kk = e >> 6, mm = e & 63;
                As[kk][mm] = A[(long)(k0 + kk) * M + m0 + mm];
            }
        } else {
#pragma unroll
            for (int i = 0; i < 4; i++) {
                int e = t + i * 256;
                int mm = e >> 4, kk = e & 15;
                As[kk][mm] = A[(long)(m0 + mm) * K + k0 + kk];
            }
        }
#pragma unroll
        for (int i = 0; i < 4; i++) {
            int e = t + i * 256;
            int kk = e >> 6, nn = e & 63;
            Bs[kk][nn] = Bm[(long)(k0 + kk) * N + n0 + nn];
        }
        __syncthreads();
#pragma unroll
        for (int kk = 0; kk < 16; kk++) {
            float a[4], bv[4];
#pragma unroll
            for (int i = 0; i < 4; i++) a[i] = As[kk][ty * 4 + i];
#pragma unroll
            for (int j = 0; j < 4; j++) bv[j] = Bs[kk][tx * 4 + j];
#pragma unroll
            for (int i = 0; i < 4; i++)
#pragma unroll
                for (int j = 0; j < 4; j++)
                    acc[i][j] += a[i] * bv[j];
        }
        __syncthreads();
    }
#pragma unroll
    for (int i = 0; i < 4; i++) {
        int gm = m0 + ty * 4 + i;
#pragma unroll
        for (int j = 0; j < 4; j++) {
            int gn = n0 + tx * 4 + j;
            long idx = (long)gm * N + gn;
            float v = acc[i][j];
            if (BIAS)  v += bias[gn];
            if (RESID) v += Cm[idx];
            if (GELU)  v = 0.5f * v * (1.0f + erff(v * 0.70710678118654752440f));
            Cm[idx] = v;
        }
    }
}

// ---------------- fused dual GEMM + GLU (+ per-batch style scale) ----------------
// h = A@B + bias (B is [K, 2*Nh]); out[r,n] = h[r,n]*sigmoid(h[r,Nh+n]) * s[bofs + r/2048, n]
template<bool HAS_S>
__global__ __launch_bounds__(256) void gemm_glu_f32(const float* __restrict__ A,
                                                    const float* __restrict__ Bm,
                                                    float* __restrict__ Cm,
                                                    int M, int Nh, int K,
                                                    const float* __restrict__ bias,
                                                    const float* __restrict__ s,
                                                    int bofs) {
    int n0 = blockIdx.x * 64;
    int m0 = blockIdx.y * 64;
    __shared__ float As[16][68];
    __shared__ float B1[16][68];
    __shared__ float B2[16][68];
    int t = threadIdx.x;
    int tx = t & 15, ty = t >> 4;
    float acc1[4][4] = {}, acc2[4][4] = {};
    const int N2 = Nh * 2;
    for (int k0 = 0; k0 < K; k0 += 16) {
#pragma unroll
        for (int i = 0; i < 4; i++) {
            int e = t + i * 256;
            int mm = e >> 4, kk = e & 15;
            As[kk][mm] = A[(long)(m0 + mm) * K + k0 + kk];
        }
#pragma unroll
        for (int i = 0; i < 4; i++) {
            int e = t + i * 256;
            int kk = e >> 6, nn = e & 63;
            const float* Brow = Bm + (long)(k0 + kk) * N2 + n0 + nn;
            B1[kk][nn] = Brow[0];
            B2[kk][nn] = Brow[Nh];
        }
        __syncthreads();
#pragma unroll
        for (int kk = 0; kk < 16; kk++) {
            float a[4], b1[4], b2[4];
#pragma unroll
            for (int i = 0; i < 4; i++) a[i] = As[kk][ty * 4 + i];
#pragma unroll
            for (int j = 0; j < 4; j++) b1[j] = B1[kk][tx * 4 + j];
#pragma unroll
            for (int j = 0; j < 4; j++) b2[j] = B2[kk][tx * 4 + j];
#pragma unroll
            for (int i = 0; i < 4; i++)
#pragma unroll
                for (int j = 0; j < 4; j++) {
                    acc1[i][j] += a[i] * b1[j];
                    acc2[i][j] += a[i] * b2[j];
                }
        }
        __syncthreads();
    }
#pragma unroll
    for (int i = 0; i < 4; i++) {
        int gm = m0 + ty * 4 + i;
#pragma unroll
        for (int j = 0; j < 4; j++) {
            int gn = n0 + tx * 4 + j;
            float av = acc1[i][j] + bias[gn];
            float gv = acc2[i][j] + bias[Nh + gn];
            float act = av * (1.0f / (1.0f + expf(-gv)));
            if (HAS_S) act *= s[((gm >> 11) + bofs) * Nh + gn];
            Cm[(long)gm * Nh + gn] = act;
        }
    }
}

extern "C" void kernel_launch(void* const* d_in, const int* in_sizes, int n_in,
                              void* d_out, int out_size, void* d_ws, size_t ws_size,
                              hipStream_t stream) {
    const float* x     = (const float*)d_in[0];
    const float* w     = (const float*)d_in[1];
    const float* ln1_g = (const float*)d_in[2];
    const float* ln1_b = (const float*)d_in[3];
    const float* ln2_g = (const float*)d_in[4];
    const float* ln2_b = (const float*)d_in[5];
    const float* g1_W  = (const float*)d_in[6];
    const float* g1_b  = (const float*)d_in[7];
    const float* s1_W  = (const float*)d_in[8];
    const float* s1_b  = (const float*)d_in[9];
    const float* m1_W  = (const float*)d_in[10];
    const float* m1_b  = (const float*)d_in[11];
    const float* g2_W  = (const float*)d_in[12];
    const float* g2_b  = (const float*)d_in[13];
    const float* s2_W  = (const float*)d_in[14];
    const float* s2_b  = (const float*)d_in[15];
    const float* m2_W  = (const float*)d_in[16];
    const float* m2_b  = (const float*)d_in[17];
    const float* gs_W  = (const float*)d_in[18];
    const float* gs_b  = (const float*)d_in[19];
    const float* ss_W  = (const float*)d_in[20];
    const float* ss_b  = (const float*)d_in[21];
    const float* ms_W  = (const float*)d_in[22];
    const float* ms_b  = (const float*)d_in[23];
    const float* r1_W  = (const float*)d_in[24];
    const float* r1_b  = (const float*)d_in[25];
    const float* r2_W  = (const float*)d_in[26];
    const float* r2_b  = (const float*)d_in[27];
    float* out = (float*)d_out;
    float* ws  = (float*)d_ws;

    // ---- workspace (75.6 MB total) ----
    // XLN [16384,768] : xln -> x2 -> x3 (in-place residuals), live steps 1-12
    // P   [16384,384] : ACT1 (s3-6) -> MIX[8,384,768]=2.36M (s7-8) -> ACTS chunk
    //                   [4096,1536]=6.29M (s10-11) -> AR (s12-13)
    // SV  [18432]
    float* XLN = ws;                          // 12,582,912 floats
    float* P   = XLN + (long)ROWS * NC;       //  6,291,456 floats
    float* SV  = P   + (long)ROWS * NTD;      //     18,432 floats
    // d_out doubles as scratch:
    //   H1 [16384,384] = out[0:6.29M], H2 = out[6.29M:12.58M]  (steps 4-8)
    //   XLN2 chunk [4096,768] = out[0:3.14M]                   (steps 9-10)
    //   final output written step 13 (last writer).
    float* H1    = out;
    float* H2    = out + (long)ROWS * NTD;
    float* MIX   = P;
    float* XLN2C = out;
    float* ACTSC = P;

    // 1. xln = LN(x)
    ln_kernel<<<ROWS, 256, 0, stream>>>(x, ln1_g, ln1_b, XLN);
    // 2. style vectors
    svec_kernel<<<72, 256, 0, stream>>>(w, s1_W, s1_b, s2_W, s2_b, ss_W, ss_b, SV);
    // 3. a1 = glu(xln@g1_W + g1_b) * s1  -> P
    gemm_glu_f32<true><<<dim3(6, 256), 256, 0, stream>>>(XLN, g1_W, P, ROWS, 384, 768, g1_b, SV, 0);
    // 4. h1 = a1 @ m1_W + m1_b -> H1 (in d_out)
    gemm_f32<false,false,false,true><<<dim3(6, 256), 256, 0, stream>>>(P, m1_W, H1, ROWS, 384, 384, 0, 0, 0, m1_b);
    // 5. a2 = glu(xln@g2_W + g2_b) * s2 -> P
    gemm_glu_f32<true><<<dim3(6, 256), 256, 0, stream>>>(XLN, g2_W, P, ROWS, 384, 768, g2_b, SV + 3072, 0);
    // 6. h2 = a2 @ m2_W + m2_b -> H2 (in d_out)
    gemm_f32<false,false,false,true><<<dim3(6, 256), 256, 0, stream>>>(P, m2_W, H2, ROWS, 384, 384, 0, 0, 0, m2_b);
    // 7. mix[b] = gelu(h1[b]^T @ xln[b])  (M=384,N=768,K=2048, batched) -> MIX (in P)
    gemm_f32<true,false,true,false><<<dim3(12, 6, NB), 256, 0, stream>>>(
        H1, XLN, MIX, NTD, NC, NT, (long)NT * NTD, (long)NT * NC, (long)NTD * NC, nullptr);
    // 8. x2 = xln + h2[b] @ mix[b]   (in place into XLN)
    gemm_f32<false,true,false,false><<<dim3(12, 32, NB), 256, 0, stream>>>(
        H2, MIX, XLN, NT, NC, NTD, (long)NT * NTD, (long)NTD * NC, (long)NT * NC, nullptr);
    // 9-11. style branch, chunked over 4 row-chunks of 4096 (1 batch-pair each)
    for (int ch = 0; ch < 4; ch++) {
        float* x2c = XLN + (long)ch * 4096 * NC;
        // 9c. xln2_chunk = LN(x2_chunk) -> d_out scratch
        ln_kernel<<<4096, 256, 0, stream>>>(x2c, ln2_g, ln2_b, XLN2C);
        // 10c. acts = glu(xln2c@gs_W + gs_b) * ss -> P   (batch offset ch*2)
        gemm_glu_f32<true><<<dim3(24, 64), 256, 0, stream>>>(XLN2C, gs_W, ACTSC, 4096, 1536, 768, gs_b, SV + 6144, ch * 2);
        // 11c. x2_chunk += acts @ ms_W + ms_b  (in place)
        gemm_f32<false,true,false,true><<<dim3(12, 64), 256, 0, stream>>>(ACTSC, ms_W, x2c, 4096, NC, 1536, 0, 0, 0, ms_b);
    }
    // 12. ar = glu(x3@r1_W + r1_b) -> P
    gemm_glu_f32<false><<<dim3(6, 256), 256, 0, stream>>>(XLN, r1_W, P, ROWS, 384, 768, r1_b, nullptr, 0);
    // 13. out = ar @ r2_W + r2_b  (final write, entire d_out)
    gemm_f32<false,false,false,true><<<dim3(12, 256), 256, 0, stream>>>(P, r2_W, out, ROWS, NC, 384, 0, 0, 0, r2_b);
}

// Round 3
// 1173.027 us; speedup vs baseline: 2.7367x; 2.7367x over previous
//
#include <hip/hip_runtime.h>
#include <hip/hip_bf16.h>
#include <math.h>

#define NB 8
#define NT 2048
#define NC 768
#define NTD 384
#define ROWS (NB*NT)   // 16384

typedef __attribute__((ext_vector_type(8))) short s8v;   // 8 bf16 (4 VGPRs)
typedef __attribute__((ext_vector_type(4))) float f4v;   // 4 fp32 acc

__device__ __forceinline__ unsigned short f2b(float f) {  // fp32->bf16 RNE
    unsigned u = __builtin_bit_cast(unsigned, f);
    return (unsigned short)((u + 0x7FFFu + ((u >> 16) & 1u)) >> 16);
}

// LDS tile: 128 rows x 32 k (bf16), row stride 32 ushorts (64B), 16B chunks
// XOR-swizzled by (row>>1)&3 -> fragment b128 reads are 2-way (free).
__device__ __forceinline__ int lds_idx(int row, int k) {
    return row * 32 + ((((k >> 3) ^ ((row >> 1) & 3)) << 3) | (k & 7));
}

// direct staging: G row-major [tileRows, ld], rows=128, k-window 32
// MODE 0: bf16 source; MODE 2: fp32 source (convert)
template<int MODE>
__device__ __forceinline__ void stage_direct(ushort* L, const void* G, int ld,
                                             int r0, int k0, int t) {
    if (MODE == 0) {
        const ushort* g = (const ushort*)G;
#pragma unroll
        for (int p = 0; p < 2; p++) {
            int e = p * 256 + t;              // ushort8 chunk id (512 total)
            int row = e >> 2, kc = (e & 3) * 8;
            uint4 v = *(const uint4*)(g + (long)(r0 + row) * ld + k0 + kc);
            int c = (kc >> 3) ^ ((row >> 1) & 3);
            *(uint4*)&L[row * 32 + c * 8] = v;
        }
    } else {
        const float* g = (const float*)G;
#pragma unroll
        for (int p = 0; p < 4; p++) {
            int e = p * 256 + t;              // float4 chunk id (1024 total)
            int row = e >> 3, kc = (e & 7) * 4;
            float4 v = *(const float4*)(g + (long)(r0 + row) * ld + k0 + kc);
            ushort4 o;
            o.x = f2b(v.x); o.y = f2b(v.y); o.z = f2b(v.z); o.w = f2b(v.w);
            int c = (kc >> 3) ^ ((row >> 1) & 3);
            *(ushort4*)&L[row * 32 + c * 8 + (kc & 7)] = o;
        }
    }
}

// scatter staging: G is [K, ld] (k-major); tile cols rr=128, k-window 32.
// MODE 1: bf16 source; MODE 2: fp32 source. Scalar; only for mix/apply (9% FLOPs).
template<int MODE>
__device__ __forceinline__ void stage_scatter(ushort* L, const void* G, int ld,
                                              int rr0, int k0, int t) {
#pragma unroll
    for (int p = 0; p < 16; p++) {
        int e = p * 256 + t;
        int kk = e >> 7, rr = e & 127;
        ushort b;
        if (MODE == 2) b = f2b(((const float*)G)[(long)(k0 + kk) * ld + rr0 + rr]);
        else           b = ((const ushort*)G)[(long)(k0 + kk) * ld + rr0 + rr];
        L[lds_idx(rr, kk)] = b;
    }
}

// ---------------- general MFMA GEMM: C = A@B (+bias)(+resid)(gelu) ----------------
// AMODE: 0=bf16 [M,K]; 1=bf16 [K,M] scatter; 2=fp32 [M,K] convert
// BMODE: 0=bf16 [N,K] (W^T direct); 1=bf16 [K,N] scatter; 2=fp32 [K,N] scatter
// EPI: 0=bf16 out; 2=gelu->bf16; 3=fp32 resid in-place; 4=resid + bf16 dual; 5=fp32 out
template<int AMODE, int BMODE, int EPI, bool HASBIAS>
__global__ __launch_bounds__(256) void gemm_mfma(
    const void* __restrict__ A, const void* __restrict__ B,
    float* __restrict__ Cf, ushort* __restrict__ Cb,
    int M, int N, int K, int lda, int ldb, int ldc,
    long sA, long sB, long sC, const float* __restrict__ bias)
{
    int z = blockIdx.z;
    const void* Az = (AMODE == 2) ? (const void*)((const float*)A + (long)z * sA)
                                  : (const void*)((const ushort*)A + (long)z * sA);
    const void* Bz = (BMODE == 2) ? (const void*)((const float*)B + (long)z * sB)
                                  : (const void*)((const ushort*)B + (long)z * sB);
    float*  Cfz = Cf ? Cf + (long)z * sC : nullptr;
    ushort* Cbz = Cb ? Cb + (long)z * sC : nullptr;

    int m0 = blockIdx.y * 128, n0 = blockIdx.x * 128;
    __shared__ alignas(16) ushort Al[4096];
    __shared__ alignas(16) ushort Bl[4096];
    int t = threadIdx.x;
    int lane = t & 63, w = t >> 6;
    int wm = (w >> 1) * 64, wn = (w & 1) * 64;
    int fr = lane & 15, q = lane >> 4;

    f4v acc[4][4];
#pragma unroll
    for (int i = 0; i < 4; i++)
#pragma unroll
        for (int j = 0; j < 4; j++) acc[i][j] = (f4v)(0.0f);

    for (int k0 = 0; k0 < K; k0 += 32) {
        if (AMODE == 1) stage_scatter<1>(Al, Az, lda, m0, k0, t);
        else            stage_direct<(AMODE == 2) ? 2 : 0>(Al, Az, lda, m0, k0, t);
        if (BMODE == 0) stage_direct<0>(Bl, Bz, ldb, n0, k0, t);
        else            stage_scatter<BMODE>(Bl, Bz, ldb, n0, k0, t);
        __syncthreads();
        s8v af[4], bf[4];
#pragma unroll
        for (int ti = 0; ti < 4; ti++) {
            int r = wm + ti * 16 + fr;
            af[ti] = *(const s8v*)&Al[r * 32 + ((q ^ ((r >> 1) & 3)) << 3)];
        }
#pragma unroll
        for (int tj = 0; tj < 4; tj++) {
            int r = wn + tj * 16 + fr;
            bf[tj] = *(const s8v*)&Bl[r * 32 + ((q ^ ((r >> 1) & 3)) << 3)];
        }
#pragma unroll
        for (int ti = 0; ti < 4; ti++)
#pragma unroll
            for (int tj = 0; tj < 4; tj++)
                acc[ti][tj] = __builtin_amdgcn_mfma_f32_16x16x32_bf16(
                    af[ti], bf[tj], acc[ti][tj], 0, 0, 0);
        __syncthreads();
    }

    int cr0 = q * 4;  // C/D: col = lane&15, row = (lane>>4)*4 + reg
#pragma unroll
    for (int ti = 0; ti < 4; ti++) {
#pragma unroll
        for (int tj = 0; tj < 4; tj++) {
            int n = n0 + wn + tj * 16 + fr;
            float bv = HASBIAS ? bias[n] : 0.0f;
#pragma unroll
            for (int r = 0; r < 4; r++) {
                int m = m0 + wm + ti * 16 + cr0 + r;
                long idx = (long)m * ldc + n;
                float v = acc[ti][tj][r] + bv;
                if (EPI == 2) {
                    v = 0.5f * v * (1.0f + erff(v * 0.70710678118654752440f));
                    Cbz[idx] = f2b(v);
                } else if (EPI == 0) {
                    Cbz[idx] = f2b(v);
                } else if (EPI == 5) {
                    Cfz[idx] = v;
                } else {  // 3, 4: fp32 residual in place
                    v += Cfz[idx];
                    Cfz[idx] = v;
                    if (EPI == 4) Cbz[idx] = f2b(v);
                }
            }
        }
    }
}

// ---------------- fused GLU GEMM: out = (A@Wv+bv)*sigmoid(A@Wg+bg)*s ----------------
// B = W^T bf16 [2Nh, K]: value rows [0,Nh), gate rows [Nh,2Nh). out bf16 [M,Nh].
template<bool HAS_S, bool AF32>
__global__ __launch_bounds__(256) void gemm_glu_mfma(
    const void* __restrict__ A, const ushort* __restrict__ Bt,
    ushort* __restrict__ Cb, int M, int Nh, int K, int lda,
    const float* __restrict__ bias, const float* __restrict__ s, int bofs)
{
    int m0 = blockIdx.y * 128, n0 = blockIdx.x * 128;
    __shared__ alignas(16) ushort Al[4096];
    __shared__ alignas(16) ushort B1[4096];
    __shared__ alignas(16) ushort B2[4096];
    int t = threadIdx.x;
    int lane = t & 63, w = t >> 6;
    int wm = (w >> 1) * 64, wn = (w & 1) * 64;
    int fr = lane & 15, q = lane >> 4;

    f4v acc1[4][4], acc2[4][4];
#pragma unroll
    for (int i = 0; i < 4; i++)
#pragma unroll
        for (int j = 0; j < 4; j++) { acc1[i][j] = (f4v)(0.0f); acc2[i][j] = (f4v)(0.0f); }

    for (int k0 = 0; k0 < K; k0 += 32) {
        stage_direct<AF32 ? 2 : 0>(Al, A, lda, m0, k0, t);
        stage_direct<0>(B1, Bt, K, n0, k0, t);
        stage_direct<0>(B2, Bt, K, Nh + n0, k0, t);
        __syncthreads();
        s8v af[4], b1f[4], b2f[4];
#pragma unroll
        for (int ti = 0; ti < 4; ti++) {
            int r = wm + ti * 16 + fr;
            af[ti] = *(const s8v*)&Al[r * 32 + ((q ^ ((r >> 1) & 3)) << 3)];
        }
#pragma unroll
        for (int tj = 0; tj < 4; tj++) {
            int r = wn + tj * 16 + fr;
            int o = r * 32 + ((q ^ ((r >> 1) & 3)) << 3);
            b1f[tj] = *(const s8v*)&B1[o];
            b2f[tj] = *(const s8v*)&B2[o];
        }
#pragma unroll
        for (int ti = 0; ti < 4; ti++)
#pragma unroll
            for (int tj = 0; tj < 4; tj++) {
                acc1[ti][tj] = __builtin_amdgcn_mfma_f32_16x16x32_bf16(af[ti], b1f[tj], acc1[ti][tj], 0, 0, 0);
                acc2[ti][tj] = __builtin_amdgcn_mfma_f32_16x16x32_bf16(af[ti], b2f[tj], acc2[ti][tj], 0, 0, 0);
            }
        __syncthreads();
    }

    int cr0 = q * 4;
#pragma unroll
    for (int ti = 0; ti < 4; ti++) {
        int bb = ((m0 + wm + ti * 16 + cr0) >> 11) + bofs;   // batch = row/2048
#pragma unroll
        for (int tj = 0; tj < 4; tj++) {
            int n = n0 + wn + tj * 16 + fr;
            float bv = bias[n], bg = bias[Nh + n];
            float sv = HAS_S ? s[(long)bb * Nh + n] : 1.0f;
#pragma unroll
            for (int r = 0; r < 4; r++) {
                int m = m0 + wm + ti * 16 + cr0 + r;
                float vv = acc1[ti][tj][r] + bv;
                float gg = acc2[ti][tj][r] + bg;
                float a = vv * (1.0f / (1.0f + expf(-gg)));
                if (HAS_S) a *= sv;
                Cb[(long)m * Nh + n] = f2b(a);
            }
        }
    }
}

// ---------------- weight cast+transpose: Wt[n*K+k] = bf16(W[k*N+n]) ----------------
__global__ __launch_bounds__(256) void castT_kernel(const float* __restrict__ W,
                                                    ushort* __restrict__ Wt, int K, int N) {
    int k = blockIdx.x * 64 + (threadIdx.x & 63);
    int n = blockIdx.y * 4 + (threadIdx.x >> 6);
    Wt[(long)n * K + k] = f2b(W[(long)k * N + n]);
}

// ---------------- LayerNorm (fp32 out), one block per row of 768 ----------------
__global__ __launch_bounds__(256) void ln_kernel(const float* __restrict__ x,
                                                 const float* __restrict__ g,
                                                 const float* __restrict__ b,
                                                 float* __restrict__ out) {
    int row = blockIdx.x;
    const float* xr = x + (long)row * NC;
    int t = threadIdx.x;
    float v0 = xr[t], v1 = xr[t + 256], v2 = xr[t + 512];
    float s = v0 + v1 + v2;
    float s2 = v0 * v0 + v1 * v1 + v2 * v2;
    for (int off = 32; off > 0; off >>= 1) {
        s  += __shfl_down(s, off, 64);
        s2 += __shfl_down(s2, off, 64);
    }
    __shared__ float ls[4], ls2[4];
    int wid = t >> 6, lane = t & 63;
    if (lane == 0) { ls[wid] = s; ls2[wid] = s2; }
    __syncthreads();
    if (t == 0) {
        float ts = ls[0] + ls[1] + ls[2] + ls[3];
        float ts2 = ls2[0] + ls2[1] + ls2[2] + ls2[3];
        float mu = ts * (1.0f / NC);
        float var = ts2 * (1.0f / NC) - mu * mu;
        ls[0] = mu;
        ls2[0] = 1.0f / sqrtf(var + 1e-6f);
    }
    __syncthreads();
    float mu = ls[0], r = ls2[0];
    float* orow = out + (long)row * NC;
    orow[t]       = (v0 - mu) * r * g[t]       + b[t];
    orow[t + 256] = (v1 - mu) * r * g[t + 256] + b[t + 256];
    orow[t + 512] = (v2 - mu) * r * g[t + 512] + b[t + 512];
}

// ---------------- style vectors (fp32): s1[8,384] | s2[8,384] | ss[8,1536] ----------------
__global__ __launch_bounds__(256) void svec_kernel(const float* __restrict__ w,
                                                   const float* __restrict__ s1W, const float* __restrict__ s1b,
                                                   const float* __restrict__ s2W, const float* __restrict__ s2b,
                                                   const float* __restrict__ ssW, const float* __restrict__ ssb,
                                                   float* __restrict__ sout) {
    int gid = blockIdx.x * 256 + threadIdx.x;   // 0..18431
    int bb = gid / 2304;
    int r  = gid % 2304;
    const float* w0 = w + (long)bb * 1024;
    const float* w1 = w0 + 512;
    float acc = 0.f;
    if (r < 384) {
        for (int k = 0; k < 512; k++) acc += w0[k] * s1W[k * 384 + r];
        sout[bb * 384 + r] = acc + s1b[r];
    } else if (r < 768) {
        int c = r - 384;
        for (int k = 0; k < 512; k++) acc += w0[k] * s2W[k * 384 + c];
        sout[3072 + bb * 384 + c] = acc + s2b[c];
    } else {
        int c = r - 768;
        for (int k = 0; k < 512; k++) acc += w1[k] * ssW[k * 1536 + c];
        sout[6144 + bb * 1536 + c] = acc + ssb[c];
    }
}

extern "C" void kernel_launch(void* const* d_in, const int* in_sizes, int n_in,
                              void* d_out, int out_size, void* d_ws, size_t ws_size,
                              hipStream_t stream) {
    const float* x     = (const float*)d_in[0];
    const float* w     = (const float*)d_in[1];
    const float* ln1_g = (const float*)d_in[2];
    const float* ln1_b = (const float*)d_in[3];
    const float* ln2_g = (const float*)d_in[4];
    const float* ln2_b = (const float*)d_in[5];
    const float* g1_W  = (const float*)d_in[6];
    const float* g1_b  = (const float*)d_in[7];
    const float* s1_W  = (const float*)d_in[8];
    const float* s1_b  = (const float*)d_in[9];
    const float* m1_W  = (const float*)d_in[10];
    const float* m1_b  = (const float*)d_in[11];
    const float* g2_W  = (const float*)d_in[12];
    const float* g2_b  = (const float*)d_in[13];
    const float* s2_W  = (const float*)d_in[14];
    const float* s2_b  = (const float*)d_in[15];
    const float* m2_W  = (const float*)d_in[16];
    const float* m2_b  = (const float*)d_in[17];
    const float* gs_W  = (const float*)d_in[18];
    const float* gs_b  = (const float*)d_in[19];
    const float* ss_W  = (const float*)d_in[20];
    const float* ss_b  = (const float*)d_in[21];
    const float* ms_W  = (const float*)d_in[22];
    const float* ms_b  = (const float*)d_in[23];
    const float* r1_W  = (const float*)d_in[24];
    const float* r1_b  = (const float*)d_in[25];
    const float* r2_W  = (const float*)d_in[26];
    const float* r2_b  = (const float*)d_in[27];
    float* out = (float*)d_out;
    char* ws = (char*)d_ws;

    // ---- ws layout (74,784,768 B <= 75.6 MB proven safe) ----
    float*  XLN = (float*)ws;                         // [16384,768] f32, 50,331,648 B
    ushort* A1b = (ushort*)(ws + 50331648);           // [16384,384] bf16 (a1/a2/MIX/ar), 12,582,912 B
    ushort* g1t = (ushort*)(ws + 62914560);           // W^T bf16 pool, 11,796,480 B
    ushort* g2t = g1t + 589824;
    ushort* m1t = g2t + 589824;
    ushort* m2t = m1t + 147456;
    ushort* gst = m2t + 147456;
    ushort* mst = gst + 2359296;
    ushort* r1t = mst + 1179648;
    ushort* r2t = r1t + 589824;
    float*  SV  = (float*)(ws + 74711040);            // 18432 f32
    ushort* MIXb = A1b;                               // [8,384,768] bf16 alias (a2 dead)

    // ---- d_out as scratch (50,331,648 B), 3 phases ----
    ushort* H1b  = (ushort*)d_out;                    // phase1: [16384,384] bf16
    ushort* H2b  = (ushort*)((char*)d_out + 12582912);
    ushort* X3b  = (ushort*)d_out;                    // phase2-3: [16384,768] bf16
    float*  X2LN = (float*)((char*)d_out + 25165824); // phase2: [4096,768] f32 chunk
    ushort* ASb  = (ushort*)((char*)d_out + 37748736);// phase2: [4096,1536] bf16 chunk

    // 0. weight casts (bf16 W^T) + style vectors + LN1
    castT_kernel<<<dim3(12, 192), 256, 0, stream>>>(g1_W, g1t, 768, 768);
    castT_kernel<<<dim3(12, 192), 256, 0, stream>>>(g2_W, g2t, 768, 768);
    castT_kernel<<<dim3(6,  96),  256, 0, stream>>>(m1_W, m1t, 384, 384);
    castT_kernel<<<dim3(6,  96),  256, 0, stream>>>(m2_W, m2t, 384, 384);
    castT_kernel<<<dim3(12, 768), 256, 0, stream>>>(gs_W, gst, 768, 3072);
    castT_kernel<<<dim3(24, 192), 256, 0, stream>>>(ms_W, mst, 1536, 768);
    castT_kernel<<<dim3(12, 192), 256, 0, stream>>>(r1_W, r1t, 768, 768);
    castT_kernel<<<dim3(6,  192), 256, 0, stream>>>(r2_W, r2t, 384, 768);
    svec_kernel<<<72, 256, 0, stream>>>(w, s1_W, s1_b, s2_W, s2_b, ss_W, ss_b, SV);
    ln_kernel<<<ROWS, 256, 0, stream>>>(x, ln1_g, ln1_b, XLN);

    // 3. a1 = glu(xln@g1_W + g1_b)*s1 -> A1b
    gemm_glu_mfma<true, true><<<dim3(3, 128), 256, 0, stream>>>(
        XLN, g1t, A1b, ROWS, 384, 768, 768, g1_b, SV, 0);
    // 4. h1 = a1@m1_W + m1_b -> H1b
    gemm_mfma<0, 0, 0, true><<<dim3(3, 128), 256, 0, stream>>>(
        A1b, m1t, nullptr, H1b, ROWS, 384, 384, 384, 384, 384, 0, 0, 0, m1_b);
    // 5. a2 -> A1b
    gemm_glu_mfma<true, true><<<dim3(3, 128), 256, 0, stream>>>(
        XLN, g2t, A1b, ROWS, 384, 768, 768, g2_b, SV + 3072, 0);
    // 6. h2 = a2@m2_W + m2_b -> H2b
    gemm_mfma<0, 0, 0, true><<<dim3(3, 128), 256, 0, stream>>>(
        A1b, m2t, nullptr, H2b, ROWS, 384, 384, 384, 384, 384, 0, 0, 0, m2_b);
    // 7. mix[b] = gelu(h1[b]^T @ xln[b]) -> MIXb   (M=384,N=768,K=2048)
    gemm_mfma<1, 2, 2, false><<<dim3(6, 3, NB), 256, 0, stream>>>(
        H1b, XLN, nullptr, MIXb, 384, 768, 2048, 384, 768, 768,
        (long)NT * 384, (long)NT * 768, (long)384 * 768, nullptr);
    // 8. x2 = xln + h2[b]@mix[b]   (fp32 in-place; M=2048,N=768,K=384)
    gemm_mfma<0, 1, 3, false><<<dim3(6, 16, NB), 256, 0, stream>>>(
        H2b, MIXb, XLN, nullptr, 2048, 768, 384, 384, 768, 768,
        (long)NT * 384, (long)384 * 768, (long)NT * 768, nullptr);
    // 9-11. style branch, 4 chunks of 4096 rows (2 batches each)
    for (int ch = 0; ch < 4; ch++) {
        float*  XLNc = XLN + (long)ch * 4096 * 768;
        ushort* X3c  = X3b + (long)ch * 4096 * 768;
        ln_kernel<<<4096, 256, 0, stream>>>(XLNc, ln2_g, ln2_b, X2LN);
        gemm_glu_mfma<true, true><<<dim3(12, 32), 256, 0, stream>>>(
            X2LN, gst, ASb, 4096, 1536, 768, 768, gs_b, SV + 6144, ch * 2);
        // x3 = x2 + as@ms_W + ms_b (fp32 in-place) + bf16 dual-write -> X3b
        gemm_mfma<0, 0, 4, true><<<dim3(6, 32), 256, 0, stream>>>(
            ASb, mst, XLNc, X3c, 4096, 768, 1536, 1536, 1536, 768, 0, 0, 0, ms_b);
    }
    // 12. ar = glu(x3@r1_W + r1_b) -> A1b
    gemm_glu_mfma<false, false><<<dim3(3, 128), 256, 0, stream>>>(
        X3b, r1t, A1b, ROWS, 384, 768, 768, r1_b, nullptr, 0);
    // 13. out = ar@r2_W + r2_b (fp32, overwrites all d_out scratch last)
    gemm_mfma<0, 0, 5, true><<<dim3(6, 128), 256, 0, stream>>>(
        A1b, r2t, out, nullptr, ROWS, 768, 384, 384, 384, 768, 0, 0, 0, r2_b);
}